// Round 3
// baseline (682.140 us; speedup 1.0000x reference)
//
#include <hip/hip_runtime.h>

// RWKV WKV forward scan — single-pass decoupled-lookback chunked scan, v2.
// B=16, T=2048, D=1024, fp32.
//
// v2 change vs v1: NO register stash (v1's 96-float/thread stash spilled to
// scratch -> ~800MB hidden traffic). Phase 3 re-reads inputs (own block's
// 196KB, L2/L3-hot) and recomputes exp. 2 channels/thread via float2.
//
// Recurrence per chain:  a = e^w·a + e^k ; b = e^w·b + e^k·v ; out = b/a.
// Affine => associative chunk composition (P,A,B):
//   compose(2∘1) = (P1P2, P2A1+A2, P2B1+B2).
//
// Grid: 128 chain-tiles (128 channels) × 16 superchunks (128 t) = 2048 blocks.
// Block: 256 thr = 64 lanes (×2ch float2) × 4 sub-chunks of 32 t.
// Ticket ordering (atomic counter) guarantees predecessor blocks were
// dispatched first -> lookback cannot deadlock under partial residency.

#define T_LEN 2048
#define D_LEN 1024
#define B_SZ  16
#define LSTEP 32                      // t-steps per thread
#define UCH   4                       // sub-chunks per block
#define TBLK  (LSTEP * UCH)           // 128 t per block
#define SUPER (T_LEN / TBLK)          // 16 superchunks
#define NTILE (B_SZ * D_LEN / 128)    // 128 chain-tiles (128 ch each)
#define NBLK  (NTILE * SUPER)         // 2048 blocks

static_assert(NTILE == 128, "ticket decode assumes NTILE=128");

__global__ __launch_bounds__(256, 4) void wkv_scan(const float* __restrict__ kg,
                                                   const float* __restrict__ vg,
                                                   const float* __restrict__ wg,
                                                   float* __restrict__ og,
                                                   unsigned* __restrict__ counter,
                                                   unsigned* __restrict__ flags,
                                                   float* __restrict__ inc) {
    __shared__ unsigned s_ticket;
    __shared__ float2 s_part[UCH][3][64];   // per-sub-chunk (P,A,B), 2 ch per lane
    __shared__ float2 s_in[3][64];          // incoming transform from lookback

    const int ch = threadIdx.x;             // 0..63
    const int u  = threadIdx.y;             // 0..3 (== wave id)

    if (ch == 0 && u == 0) s_ticket = atomicAdd(counter, 1u);
    __syncthreads();
    const unsigned ticket = s_ticket;
    const int tile = (int)(ticket & (NTILE - 1));
    const int s    = (int)(ticket >> 7);    // superchunk index

    const int cp = tile * 64 + ch;          // chain-pair id, 0..8191
    const int bb = cp >> 9;                 // batch  (cp / 512)
    const int dd = (cp & 511) << 1;         // channel (even)
    const int t0 = s * TBLK + u * LSTEP;
    const size_t base = (size_t)bb * T_LEN * D_LEN + (size_t)t0 * D_LEN + dd;
    const size_t b2   = base >> 1;          // float2 index
    const size_t st2  = D_LEN >> 1;         // float2 stride per t

    const float2* k2 = (const float2*)kg;
    const float2* v2 = (const float2*)vg;
    const float2* w2 = (const float2*)wg;

    // ---- phase 1: stream own sub-chunk, accumulate (P,A,B) — no stash ----
    float Px = 1.f, Ax = 0.f, Bx = 0.f;
    float Py = 1.f, Ay = 0.f, By = 0.f;
#pragma unroll
    for (int j = 0; j < LSTEP; ++j) {
        const size_t o = b2 + (size_t)j * st2;
        const float2 kk = k2[o];
        const float2 vv = v2[o];
        const float2 ww = w2[o];
        const float e1x = __expf(ww.x), e2x = __expf(kk.x);
        const float e1y = __expf(ww.y), e2y = __expf(kk.y);
        Ax = e1x * Ax + e2x;  Bx = e1x * Bx + e2x * vv.x;  Px *= e1x;
        Ay = e1y * Ay + e2y;  By = e1y * By + e2y * vv.y;  Py *= e1y;
    }
    s_part[u][0][ch] = make_float2(Px, Py);
    s_part[u][1][ch] = make_float2(Ax, Ay);
    s_part[u][2][ch] = make_float2(Bx, By);
    __syncthreads();

    // ---- phase 2: wave 0 combines sub-chunks + decoupled lookback ----
    if (u == 0) {
        float2 Pf = s_part[0][0][ch], Af = s_part[0][1][ch], Bf = s_part[0][2][ch];
#pragma unroll
        for (int q = 1; q < UCH; ++q) {
            const float2 Pq = s_part[q][0][ch];
            const float2 Aq = s_part[q][1][ch];
            const float2 Bq = s_part[q][2][ch];
            Af.x = Pq.x * Af.x + Aq.x;  Af.y = Pq.y * Af.y + Aq.y;
            Bf.x = Pq.x * Bf.x + Bq.x;  Bf.y = Pq.y * Bf.y + Bq.y;
            Pf.x *= Pq.x;               Pf.y *= Pq.y;
        }

        float2 Pin = make_float2(1.f, 1.f);
        float2 Ain = make_float2(0.f, 0.f);
        float2 Bin = make_float2(0.f, 0.f);
        if (s > 0) {
            const int fidx = tile * SUPER + (s - 1);
            while (__hip_atomic_load(&flags[fidx], __ATOMIC_ACQUIRE,
                                     __HIP_MEMORY_SCOPE_AGENT) == 0u) {
                __builtin_amdgcn_s_sleep(2);
            }
            const float2* ib = (const float2*)(inc + (size_t)fidx * 384);
            Pin = ib[0 * 64 + ch];
            Ain = ib[1 * 64 + ch];
            Bin = ib[2 * 64 + ch];
        }
        if (s < SUPER - 1) {
            const int oidx = tile * SUPER + s;
            float2* ob = (float2*)(inc + (size_t)oidx * 384);
            ob[0 * 64 + ch] = make_float2(Pin.x * Pf.x,        Pin.y * Pf.y);
            ob[1 * 64 + ch] = make_float2(Pf.x * Ain.x + Af.x, Pf.y * Ain.y + Af.y);
            ob[2 * 64 + ch] = make_float2(Pf.x * Bin.x + Bf.x, Pf.y * Bin.y + Bf.y);
            __hip_atomic_store(&flags[oidx], 1u, __ATOMIC_RELEASE,
                               __HIP_MEMORY_SCOPE_AGENT);
        }
        s_in[0][ch] = Pin;
        s_in[1][ch] = Ain;
        s_in[2][ch] = Bin;
    }
    __syncthreads();

    // ---- phase 3: start state = incoming ∘ sub-chunk prefix; replay by
    //      re-reading inputs (L2/L3-hot) and recomputing exp; write out ----
    float2 Ai = s_in[1][ch], Bi = s_in[2][ch];
#pragma unroll
    for (int q = 0; q < UCH - 1; ++q) {
        if (q < u) {   // wave-uniform (u constant per wave)
            const float2 Pq = s_part[q][0][ch];
            const float2 Aq = s_part[q][1][ch];
            const float2 Bq = s_part[q][2][ch];
            Ai.x = Pq.x * Ai.x + Aq.x;  Ai.y = Pq.y * Ai.y + Aq.y;
            Bi.x = Pq.x * Bi.x + Bq.x;  Bi.y = Pq.y * Bi.y + Bq.y;
        }
    }

    float ax = Ai.x, bx = Bi.x, ay = Ai.y, by = Bi.y;
    float2* o2 = (float2*)og;
#pragma unroll
    for (int j = 0; j < LSTEP; ++j) {
        const size_t o = b2 + (size_t)j * st2;
        const float2 kk = k2[o];
        const float2 vv = v2[o];
        const float2 ww = w2[o];
        const float e1x = __expf(ww.x), e2x = __expf(kk.x);
        const float e1y = __expf(ww.y), e2y = __expf(kk.y);
        ax = e1x * ax + e2x;  bx = e1x * bx + e2x * vv.x;
        ay = e1y * ay + e2y;  by = e1y * by + e2y * vv.y;
        o2[o] = make_float2(__fdividef(bx, ax), __fdividef(by, ay));
    }
}

extern "C" void kernel_launch(void* const* d_in, const int* in_sizes, int n_in,
                              void* d_out, int out_size, void* d_ws, size_t ws_size,
                              hipStream_t stream) {
    const float* k = (const float*)d_in[0];
    const float* v = (const float*)d_in[1];
    const float* w = (const float*)d_in[2];
    float* out = (float*)d_out;

    // ws layout: [0,4) ticket counter | [256, 256+8K) flags | then inc payload
    unsigned* counter = (unsigned*)d_ws;
    unsigned* flags   = (unsigned*)((char*)d_ws + 256);
    float*    inc     = (float*)((char*)d_ws + 256 + NBLK * sizeof(unsigned));

    hipMemsetAsync(d_ws, 0, 256 + NBLK * sizeof(unsigned), stream);

    wkv_scan<<<dim3(NBLK), dim3(64, UCH), 0, stream>>>(k, v, w, out,
                                                       counter, flags, inc);
}